// Round 1
// baseline (2290.651 us; speedup 1.0000x reference)
//
#include <hip/hip_runtime.h>

// RITS-I recurrent imputation kernel, fp32, one workgroup per batch row.
// B=256, T=2048, I=64, H=32, gates=128.

#define LBAR() do { asm volatile("s_waitcnt lgkmcnt(0)" ::: "memory"); __builtin_amdgcn_s_barrier(); } while (0)

__device__ __forceinline__ float sigm(float x) {
  return __builtin_amdgcn_rcpf(1.f + __expf(-x));
}
__device__ __forceinline__ float tanh_fast(float x) {
  // tanh(x) = 1 - 2/(exp(2x)+1); saturates correctly at +-1 for |x| large
  return 1.f - 2.f * __builtin_amdgcn_rcpf(1.f + __expf(2.f * x));
}

__global__ __launch_bounds__(256, 1) void rits_kernel(
    const float* __restrict__ values, const float* __restrict__ masks,
    const float* __restrict__ deltas,
    const float* __restrict__ W_decay, const float* __restrict__ b_decay,
    const float* __restrict__ W_reg,  const float* __restrict__ b_reg,
    const float* __restrict__ W_ih,   const float* __restrict__ b_ih,
    const float* __restrict__ W_hh,   const float* __restrict__ b_hh,
    const float* __restrict__ W_out,  const float* __restrict__ b_out,
    float* __restrict__ y_out, float* __restrict__ imp_out)
{
  constexpr int T = 2048, I = 64, CH = 8, NCH = T / CH;
  const int tid  = threadIdx.x;
  const int b    = blockIdx.x;
  const int wv   = tid >> 6;       // wave id 0..3
  const int g    = tid & 127;      // gate index (2 threads per gate)
  const int half = tid >> 7;       // input-half owned by this thread

  __shared__ float WdecT[64][32];              // [k][j] = W_decay[j][k]
  __shared__ float WregT[32][64];              // [j][i] = W_reg[i][j]
  __shared__ float h_s[32], c_s[32];
  __shared__ float xc_s[64];
  __shared__ float gpart[2][128];
  __shared__ __align__(16) float stage[2][3 * CH * 64]; // [buf][stream*512 + s*64 + i]

  // ---- one-time: transposed small weights into LDS ----
  for (int idx = tid; idx < 64 * 32; idx += 256) {
    int k = idx >> 5, j = idx & 31;
    WdecT[k][j] = W_decay[j * 64 + k];
  }
  for (int idx = tid; idx < 32 * 64; idx += 256) {
    int j = idx >> 6, i = idx & 63;
    WregT[j][i] = W_reg[i * 32 + j];
  }
  if (tid < 32) { h_s[tid] = 0.f; c_s[tid] = 0.f; }

  // ---- one-time: gate weights into registers (static-indexed arrays) ----
  float wxc[32], wm[32], wh[16];
  {
    const float* wr = W_ih + g * 128 + half * 32;
    #pragma unroll
    for (int u = 0; u < 32; ++u) wxc[u] = wr[u];        // W_ih[g][half*32+u]     (x_c part)
    #pragma unroll
    for (int u = 0; u < 32; ++u) wm[u] = wr[64 + u];    // W_ih[g][64+half*32+u]  (m part)
    const float* wr2 = W_hh + g * 32 + half * 16;
    #pragma unroll
    for (int u = 0; u < 16; ++u) wh[u] = wr2[u];        // W_hh[g][half*16+u]
  }
  const float bgr   = (half == 0) ? (b_ih[g] + b_hh[g]) : 0.f;
  const float bdecr = b_decay[tid & 31];
  const float bregr = b_reg[tid & 63];

  // ---- streaming sources, register-prefetched chunk staging ----
  const size_t bb = (size_t)b * T * I;
  const float* pA = (tid < 128) ? (values + bb) : (masks + bb);
  const int    qA = (tid & 127) * 4;
  const float* pB = deltas + bb;   // second load only for tid<128
  const int    qB = tid * 4;

  float4 rA, rB;
  rA = *(const float4*)(pA + qA);
  if (tid < 128) rB = *(const float4*)(pB + qB);

  float* imp_b = imp_out + bb;

  for (int ch = 0; ch < NCH; ++ch) {
    const int cur = ch & 1;
    float* st = &stage[cur][0];
    // write prefetched regs -> LDS (compiler inserts the vmcnt wait on rA/rB)
    *(float4*)(st + tid * 4) = rA;
    if (tid < 128) *(float4*)(st + 1024 + tid * 4) = rB;
    // issue next chunk's loads; they stay in flight across the 8 steps
    if (ch + 1 < NCH) {
      const size_t off = (size_t)(ch + 1) * (CH * I);
      rA = *(const float4*)(pA + off + qA);
      if (tid < 128) rB = *(const float4*)(pB + off + qB);
    }
    LBAR();

    const float* xs_base = st;
    const float* ms_base = st + 512;
    const float* ds_base = st + 1024;

    for (int s = 0; s < CH; ++s) {
      const int t = ch * CH + s;
      const float* xs  = xs_base + s * 64;
      const float* ms  = ms_base + s * 64;
      const float* dsv = ds_base + s * 64;

      // ---- Phase A: gamma + h decay (wave 2) || gates m-part (all threads)
      if (wv == 2) {
        const int lane = tid - 128;
        const int j = lane & 31, dh = lane >> 5;
        float ga = 0.f;
        #pragma unroll
        for (int u = 0; u < 32; ++u) {
          const int k = dh * 32 + u;
          ga = fmaf(dsv[k], WdecT[k][j], ga);
        }
        ga += __shfl_xor(ga, 32);
        if (dh == 0) {
          const float z = fmaxf(ga + bdecr, 0.f);
          h_s[j] *= __expf(-z);
        }
      }
      float am = bgr;
      #pragma unroll
      for (int u = 0; u < 32; ++u) am = fmaf(ms[half * 32 + u], wm[u], am);
      LBAR();   // decayed h visible

      // ---- Phase B: gates h-part (all) || x_h, x_c, imputation store (wave 1)
      float ah = 0.f;
      #pragma unroll
      for (int u = 0; u < 16; ++u) ah = fmaf(h_s[half * 16 + u], wh[u], ah);
      if (wv == 1) {
        const int i = tid - 64;
        float xh = bregr;
        #pragma unroll
        for (int jj = 0; jj < 32; ++jj) xh = fmaf(h_s[jj], WregT[jj][i], xh);
        const float m = ms[i], x = xs[i];
        const float xc = fmaf(m, x, (1.f - m) * xh);
        xc_s[i] = xc;
        imp_b[(size_t)t * I + i] = xc;
      }
      LBAR();   // xc_s visible

      // ---- Phase C: gates x_c-part, write partials
      float ac = am + ah;
      #pragma unroll
      for (int u = 0; u < 32; ++u) ac = fmaf(xc_s[half * 32 + u], wxc[u], ac);
      gpart[half][g] = ac;
      LBAR();   // partials visible

      // ---- Phase D: LSTM pointwise (threads 0..31)
      if (tid < 32) {
        const int j = tid;
        const float gi = gpart[0][j]      + gpart[1][j];
        const float gf = gpart[0][32 + j] + gpart[1][32 + j];
        const float gg = gpart[0][64 + j] + gpart[1][64 + j];
        const float go = gpart[0][96 + j] + gpart[1][96 + j];
        const float cn = sigm(gf) * c_s[j] + sigm(gi) * tanh_fast(gg);
        h_s[j] = sigm(go) * tanh_fast(cn);
        c_s[j] = cn;
      }
      LBAR();   // h,c update visible for next step
    }
  }

  // ---- final classification head: y = h @ W_out^T + b_out ----
  if (tid < 2) {
    float acc = b_out[tid];
    #pragma unroll
    for (int jj = 0; jj < 32; ++jj) acc = fmaf(h_s[jj], W_out[tid * 32 + jj], acc);
    y_out[b * 2 + tid] = acc;
  }
}

extern "C" void kernel_launch(void* const* d_in, const int* in_sizes, int n_in,
                              void* d_out, int out_size, void* d_ws, size_t ws_size,
                              hipStream_t stream) {
  const float* values  = (const float*)d_in[0];
  const float* masks   = (const float*)d_in[1];
  const float* deltas  = (const float*)d_in[2];
  const float* W_decay = (const float*)d_in[3];
  const float* b_decay = (const float*)d_in[4];
  const float* W_reg   = (const float*)d_in[5];
  const float* b_reg   = (const float*)d_in[6];
  const float* W_ih    = (const float*)d_in[7];
  const float* b_ih    = (const float*)d_in[8];
  const float* W_hh    = (const float*)d_in[9];
  const float* b_hh    = (const float*)d_in[10];
  const float* W_out   = (const float*)d_in[11];
  const float* b_out   = (const float*)d_in[12];
  float* y   = (float*)d_out;
  float* imp = (float*)d_out + 512;   // outputs: y_h [256,2] then imputations [256,2048,64]

  hipLaunchKernelGGL(rits_kernel, dim3(256), dim3(256), 0, stream,
                     values, masks, deltas, W_decay, b_decay, W_reg, b_reg,
                     W_ih, b_ih, W_hh, b_hh, W_out, b_out, y, imp);
}